// Round 3
// baseline (591.170 us; speedup 1.0000x reference)
//
#include <hip/hip_runtime.h>

#define NN 100000
#define NE 1600000
#define NE2 1700000
#define OUT_EI 3200000
#define OUT_AL 6600000
#define SLOPE 0.2f
#define NB 391       // ceil(NN/256): dst buckets (256 nodes each)
#define EPB 6400     // edges per block in binning kernels
#define NBB 250      // NE / EPB
#define NNP 100096   // NN padded for aliased sub-buffers

typedef unsigned short u16;
typedef unsigned int u32;
typedef __bf16 bf16x8 __attribute__((ext_vector_type(8)));
typedef float f32x4 __attribute__((ext_vector_type(4)));
typedef u32 u32x4 __attribute__((ext_vector_type(4)));

__device__ __forceinline__ float bf2f(u16 u){ return __uint_as_float(((u32)u) << 16); }
__device__ __forceinline__ u16 f2bf(float f){
    u32 x = __float_as_uint(f);
    x += 0x7FFFu + ((x >> 16) & 1u);   // round-to-nearest-even
    return (u16)(x >> 16);
}
__device__ __forceinline__ float eluf(float v){ return v > 0.f ? v : (__expf(v) - 1.f); }
__device__ __forceinline__ float lreluf(float v){ return fmaxf(v, SLOPE * v); }
__device__ __forceinline__ float sel4f(float a, float b, float c, float d, int s){
    float x = (s & 1) ? b : a;
    float y = (s & 1) ? d : c;
    return (s & 2) ? y : x;
}

// ================= bucketed CSR build =================
__global__ __launch_bounds__(256) void k_bhist(const int* __restrict__ ei, int* __restrict__ bcnt){
    __shared__ int s[NB];
    int t = threadIdx.x;
    for (int i = t; i < NB; i += 256) s[i] = 0;
    __syncthreads();
    int e0 = blockIdx.x * EPB;
    for (int i = t; i < EPB; i += 256)
        atomicAdd(&s[ei[NE + e0 + i] >> 8], 1);
    __syncthreads();
    for (int i = t; i < NB; i += 256) if (s[i]) atomicAdd(&bcnt[i], s[i]);
}

__global__ void k_bscan(const int* __restrict__ bcnt, int* __restrict__ bbase, int* __restrict__ bcur){
    __shared__ int s[512];
    int t = threadIdx.x;                              // 512 threads
    int v = (t < NB) ? bcnt[t] : 0;
    s[t] = v; __syncthreads();
    #pragma unroll
    for (int d = 1; d < 512; d <<= 1){
        int x = (t >= d) ? s[t - d] : 0;
        __syncthreads();
        s[t] += x;
        __syncthreads();
    }
    if (t < NB){ int ex = s[t] - v; bbase[t] = ex; bcur[t] = ex; }
    if (t == 0) bbase[NB] = NE;
}

// bucket scatter: block-aggregated chunk reservation -> dense write runs per bucket.
// payload read SEQUENTIALLY; packed bin = (dstLow8 << 24) | src24.
__global__ __launch_bounds__(256) void k_bscatter(const int* __restrict__ ei, const u16* __restrict__ ale1,
                                                  const u16* __restrict__ ale2,
                                                  int* __restrict__ bcur, u32* __restrict__ binsP,
                                                  uint2* __restrict__ binsA, u16* __restrict__ binsA2){
    __shared__ int cnt[NB];
    __shared__ int base[NB];
    __shared__ int sdst[EPB];
    int t = threadIdx.x;
    for (int i = t; i < NB; i += 256) cnt[i] = 0;
    __syncthreads();
    int e0 = blockIdx.x * EPB;
    for (int i = t; i < EPB; i += 256){
        int dv = ei[NE + e0 + i];
        sdst[i] = dv;
        atomicAdd(&cnt[dv >> 8], 1);
    }
    __syncthreads();
    for (int i = t; i < NB; i += 256){
        int c = cnt[i];
        base[i] = c ? atomicAdd(&bcur[i], c) : 0;
        cnt[i] = 0;
    }
    __syncthreads();
    const uint2* a1 = (const uint2*)ale1;
    for (int i = t; i < EPB; i += 256){
        int e = e0 + i;
        int dst = sdst[i];
        int b = dst >> 8;
        int r = atomicAdd(&cnt[b], 1);
        int pos = base[b] + r;
        binsP[pos] = ((u32)(dst & 255) << 24) | (u32)ei[e];
        binsA[pos] = a1[e];
        binsA2[pos] = ale2[e];
    }
}

// merged: per-bucket degree hist + 256-wide scan -> offsets + fine scatter (LDS cursors)
__global__ __launch_bounds__(256) void k_fscatter(const u32* __restrict__ binsP, const uint2* __restrict__ binsA,
                                                  const u16* __restrict__ binsA2, const int* __restrict__ bbase,
                                                  int* __restrict__ offsets,
                                                  int* __restrict__ src32, uint2* __restrict__ ale1p,
                                                  u16* __restrict__ ale2p){
    __shared__ int d[256];
    __shared__ int s[256];
    __shared__ int cur[256];
    int t = threadIdx.x, b = blockIdx.x;
    d[t] = 0;
    __syncthreads();
    int bs = bbase[b], be = bbase[b + 1];
    for (int i = bs + t; i < be; i += 256)
        atomicAdd(&d[binsP[i] >> 24], 1);
    __syncthreads();
    int v = d[t];
    s[t] = v; __syncthreads();
    #pragma unroll
    for (int dd = 1; dd < 256; dd <<= 1){
        int x = (t >= dd) ? s[t - dd] : 0;
        __syncthreads();
        s[t] += x;
        __syncthreads();
    }
    int n = b * 256 + t;
    int off = bs + (s[t] - v) + n;            // bucket base + in-bucket prefix + self slots
    if (n < NN) offsets[n] = off;
    cur[t] = off + 1;                          // real edges start after self-loop slot
    if (b == 0 && t == 0) offsets[NN] = NE + NN;
    __syncthreads();
    for (int i = bs + t; i < be; i += 256){
        u32 p = binsP[i];
        int dl = p >> 24;
        int pos = atomicAdd(&cur[dl], 1);
        src32[pos] = (int)(p & 0xFFFFFFu);
        ale1p[pos] = binsA[i];
        ale2p[pos] = binsA2[i];
    }
}

// ================= small precomputes =================
__global__ void k_q(const float* __restrict__ W1e, const float* __restrict__ a1e,
                    const float* __restrict__ W2e, const float* __restrict__ a2e,
                    float* __restrict__ q1, float* __restrict__ q2){
    int t = threadIdx.x;           // 64 threads
    int k = t >> 2, h = t & 3;
    float s = 0.f;
    for (int c = 0; c < 32; c++) s += W1e[k * 128 + h * 32 + c] * a1e[h * 32 + c];
    q1[t] = s;
    if (t < 16){
        float s2 = 0.f;
        for (int c = 0; c < 32; c++) s2 += W2e[t * 32 + c] * a2e[c];
        q2[t] = s2;
    }
}

__global__ __launch_bounds__(256) void k_ale(const float* __restrict__ eattr,
                                             const float* __restrict__ q1, const float* __restrict__ q2,
                                             u16* __restrict__ ale1, u16* __restrict__ ale2){
    __shared__ float sq1[64], sq2[16];
    int t = threadIdx.x;
    if (t < 64) sq1[t] = q1[t];
    if (t < 16) sq2[t] = q2[t];
    __syncthreads();
    int gt = blockIdx.x * 256 + t;                   // NE*4 exact
    int e = gt >> 2, part = gt & 3;
    f32x4 av = ((const f32x4*)eattr)[(size_t)e * 4 + part];
    int j0 = part * 4;
    float p0 = 0, p1 = 0, p2 = 0, p3 = 0, p4 = 0;
    #pragma unroll
    for (int k = 0; k < 4; k++){
        float a = av[k]; int j = j0 + k;
        p0 += a * sq1[j * 4 + 0]; p1 += a * sq1[j * 4 + 1];
        p2 += a * sq1[j * 4 + 2]; p3 += a * sq1[j * 4 + 3];
        p4 += a * sq2[j];
    }
    #pragma unroll
    for (int m = 1; m < 4; m <<= 1){
        p0 += __shfl_xor(p0, m); p1 += __shfl_xor(p1, m);
        p2 += __shfl_xor(p2, m); p3 += __shfl_xor(p3, m); p4 += __shfl_xor(p4, m);
    }
    if (part == 0){
        ushort4 w; w.x = f2bf(p0); w.y = f2bf(p1); w.z = f2bf(p2); w.w = f2bf(p3);
        ((ushort4*)ale1)[e] = w;
        ale2[e] = f2bf(p4);
    }
}

// ================= GEMM 1 (with fused al_s1/al_d1 epilogue) =================
__global__ __launch_bounds__(256) void k_gemm1(const float* __restrict__ x, const float* __restrict__ W,
                                               const float* __restrict__ a1s, const float* __restrict__ a1d,
                                               u16* __restrict__ h1,
                                               float* __restrict__ al_s, float* __restrict__ al_d){
    __shared__ __align__(16) u16 sW[128 * 136];      // transposed: sW[col*136+k]
    int t = threadIdx.x;
    for (int i = t; i < 128 * 128; i += 256){
        int k = i >> 7, c = i & 127;
        sW[c * 136 + k] = f2bf(W[i]);
    }
    __syncthreads();
    int lane = t & 63, wave = t >> 6;
    int quad = lane >> 4, m16 = lane & 15;
    int rowA = blockIdx.x * 64 + wave * 16 + m16;
    bf16x8 afr[4];
    if (rowA < NN){
        const f32x4* xr = (const f32x4*)(x + (size_t)rowA * 128);
        #pragma unroll
        for (int kk = 0; kk < 4; kk++){
            f32x4 va = xr[kk * 8 + quad * 2];
            f32x4 vb = xr[kk * 8 + quad * 2 + 1];
            #pragma unroll
            for (int i2 = 0; i2 < 4; i2++){ afr[kk][i2] = (__bf16)va[i2]; afr[kk][4 + i2] = (__bf16)vb[i2]; }
        }
    } else {
        #pragma unroll
        for (int kk = 0; kk < 4; kk++)
            #pragma unroll
            for (int i2 = 0; i2 < 8; i2++) afr[kk][i2] = (__bf16)0.f;
    }
    int rowbase = blockIdx.x * 64 + wave * 16 + quad * 4;
    float vsA[4][4], vdA[4][4];
    #pragma unroll
    for (int r = 0; r < 4; r++)
        #pragma unroll
        for (int h = 0; h < 4; h++){ vsA[r][h] = 0.f; vdA[r][h] = 0.f; }
    #pragma unroll
    for (int nt = 0; nt < 8; nt++){
        f32x4 acc = (f32x4){0.f, 0.f, 0.f, 0.f};
        const u16* wp = &sW[(nt * 16 + m16) * 136 + quad * 8];
        #pragma unroll
        for (int kk = 0; kk < 4; kk++){
            bf16x8 bfr = *(const bf16x8*)(wp + kk * 32);
            acc = __builtin_amdgcn_mfma_f32_16x16x32_bf16(afr[kk], bfr, acc, 0, 0, 0);
        }
        int col = nt * 16 + m16;
        float cs = a1s[col], cd = a1d[col];
        const int h = nt >> 1;                       // head uniform per nt
        #pragma unroll
        for (int r = 0; r < 4; r++){
            vsA[r][h] += acc[r] * cs;
            vdA[r][h] += acc[r] * cd;
            int row = rowbase + r;
            if (row < NN) h1[(size_t)row * 128 + col] = f2bf(acc[r]);
        }
    }
    #pragma unroll
    for (int r = 0; r < 4; r++)
        #pragma unroll
        for (int h = 0; h < 4; h++)
            #pragma unroll
            for (int m = 1; m < 16; m <<= 1){
                vsA[r][h] += __shfl_xor(vsA[r][h], m);
                vdA[r][h] += __shfl_xor(vdA[r][h], m);
            }
    int rs = m16 >> 2, hs = m16 & 3;                 // lane m16 writes (row rs, head hs)
    float s0 = sel4f(vsA[0][0], vsA[0][1], vsA[0][2], vsA[0][3], hs);
    float s1 = sel4f(vsA[1][0], vsA[1][1], vsA[1][2], vsA[1][3], hs);
    float s2 = sel4f(vsA[2][0], vsA[2][1], vsA[2][2], vsA[2][3], hs);
    float s3 = sel4f(vsA[3][0], vsA[3][1], vsA[3][2], vsA[3][3], hs);
    float d0 = sel4f(vdA[0][0], vdA[0][1], vdA[0][2], vdA[0][3], hs);
    float d1 = sel4f(vdA[1][0], vdA[1][1], vdA[1][2], vdA[1][3], hs);
    float d2 = sel4f(vdA[2][0], vdA[2][1], vdA[2][2], vdA[2][3], hs);
    float d3 = sel4f(vdA[3][0], vdA[3][1], vdA[3][2], vdA[3][3], hs);
    float souts = sel4f(s0, s1, s2, s3, rs);
    float soutd = sel4f(d0, d1, d2, d3, rs);
    int row = rowbase + rs;
    if (row < NN){
        al_s[row * 4 + hs] = souts;
        al_d[row * 4 + hs] = soutd;
    }
}

// ================= layer 1 node kernel: softmax+aggregate FUSED with gemm2+al2 =================
// 8-lane groups (8 edges in flight), 3-deep software pipeline.
// After aggregation, the node's fp32 layer-1 output row (post-ELU) is staged in LDS and
// multiplied by W2 (fp32, LDS) to produce h2a + al_s2/al_d2 directly. h1b eliminated.
__global__ __launch_bounds__(256) void k_node1(const int* __restrict__ src32, const u16* __restrict__ ale1u,
                                               const int* __restrict__ offsets,
                                               const float* __restrict__ al_s, const float* __restrict__ al_d,
                                               const u16* __restrict__ h1, const float* __restrict__ b1,
                                               const float* __restrict__ W2,
                                               const float* __restrict__ a2s, const float* __restrict__ a2d,
                                               float* __restrict__ h2a,
                                               float* __restrict__ al_s2, float* __restrict__ al_d2){
    __shared__ float sW2[128 * 32];                  // [k][c], 16 KB
    __shared__ float sh1[4][128];                    // per-wave fp32 layer-1 row
    int t = threadIdx.x;
    for (int i = t; i < 128 * 32; i += 256) sW2[i] = W2[i];
    int wave = t >> 6, lane = t & 63;
    int n = blockIdx.x * 4 + wave;                   // NN/4 blocks exact
    int start = offsets[n], end = offsets[n + 1];
    int degr = end - start - 1;
    int g = lane >> 3, l = lane & 7, hq = l >> 1;    // lane channels 16l..16l+15, head = l>>1
    float aldh = al_d[n * 4 + hq];
    const u32x4* h1v = (const u32x4*)h1;             // 16 u32x4 per row
    float acc[16];
    #pragma unroll
    for (int k = 0; k < 16; k++) acc[k] = 0.f;
    float z = 0.f, sa = 0.f;
    // 3-deep pipeline: src 2 ahead, payload 1 ahead
    int i = start + 1 + g;
    int i1 = i + 8, i2 = i + 16;
    int src0 = (i  < end) ? __builtin_nontemporal_load(src32 + i)  : n;
    int src1 = (i1 < end) ? __builtin_nontemporal_load(src32 + i1) : n;
    float a0   = (i < end) ? bf2f(__builtin_nontemporal_load(ale1u + (size_t)i * 4 + hq)) : 0.f;
    float als0 = al_s[src0 * 4 + hq];
    u32x4 v00 = h1v[(size_t)src0 * 16 + 2 * l];
    u32x4 v01 = h1v[(size_t)src0 * 16 + 2 * l + 1];
    while (i < end){
        int src2 = (i2 < end) ? __builtin_nontemporal_load(src32 + i2) : n;
        float a1v   = (i1 < end) ? bf2f(__builtin_nontemporal_load(ale1u + (size_t)i1 * 4 + hq)) : 0.f;
        float als1 = al_s[src1 * 4 + hq];
        u32x4 v10 = h1v[(size_t)src1 * 16 + 2 * l];
        u32x4 v11 = h1v[(size_t)src1 * 16 + 2 * l + 1];
        float e = __expf(lreluf(als0 + aldh + a0));
        z += e; sa += a0;
        #pragma unroll
        for (int k = 0; k < 4; k++){
            acc[2 * k]     += e * bf2f((u16)(v00[k] & 0xFFFFu));
            acc[2 * k + 1] += e * bf2f((u16)(v00[k] >> 16));
            acc[8 + 2 * k] += e * bf2f((u16)(v01[k] & 0xFFFFu));
            acc[9 + 2 * k] += e * bf2f((u16)(v01[k] >> 16));
        }
        i = i1; i1 = i2; i2 += 8;
        src1 = src2; a0 = a1v; als0 = als1; v00 = v10; v01 = v11;
    }
    z += __shfl_xor(z, 8); z += __shfl_xor(z, 16); z += __shfl_xor(z, 32);
    sa += __shfl_xor(sa, 8); sa += __shfl_xor(sa, 16); sa += __shfl_xor(sa, 32);
    float inv_deg = 1.f / fmaxf((float)degr, 1.f);
    float ps = __expf(lreluf(al_s[n * 4 + hq] + aldh + sa * inv_deg));
    z += ps;
    if (g == 0){                                     // self contribution, counted once
        u32x4 s0 = h1v[(size_t)n * 16 + 2 * l];
        u32x4 s1 = h1v[(size_t)n * 16 + 2 * l + 1];
        #pragma unroll
        for (int k = 0; k < 4; k++){
            acc[2 * k]     += ps * bf2f((u16)(s0[k] & 0xFFFFu));
            acc[2 * k + 1] += ps * bf2f((u16)(s0[k] >> 16));
            acc[8 + 2 * k] += ps * bf2f((u16)(s1[k] & 0xFFFFu));
            acc[9 + 2 * k] += ps * bf2f((u16)(s1[k] >> 16));
        }
    }
    #pragma unroll
    for (int k = 0; k < 16; k++){
        acc[k] += __shfl_xor(acc[k], 8);
        acc[k] += __shfl_xor(acc[k], 16);
        acc[k] += __shfl_xor(acc[k], 32);
    }
    if (g == 0){                                     // lanes 0..7 hold channels 16l..16l+15
        float rz = 1.f / z;
        float* dst = &sh1[wave][16 * l];
        #pragma unroll
        for (int q = 0; q < 4; q++){
            f32x4 w;
            #pragma unroll
            for (int k = 0; k < 4; k++)
                w[k] = eluf(acc[4 * q + k] * rz + b1[16 * l + 4 * q + k]);
            ((f32x4*)dst)[q] = w;
        }
    }
    __syncthreads();                                 // sW2 ready + sh1 rows visible
    // --- fused gemm2 + al2 epilogue: h2a[n] = sh1[wave] @ W2 (fp32) ---
    int c = lane & 31, half = lane >> 5;
    const float* hr = sh1[wave];
    float s = 0.f;
    #pragma unroll
    for (int k = half * 64; k < half * 64 + 64; k += 4){
        f32x4 hv = *(const f32x4*)(hr + k);
        s += hv[0] * sW2[(k + 0) * 32 + c] + hv[1] * sW2[(k + 1) * 32 + c]
           + hv[2] * sW2[(k + 2) * 32 + c] + hv[3] * sW2[(k + 3) * 32 + c];
    }
    s += __shfl_xor(s, 32);
    float vs = s * a2s[c], vd = s * a2d[c];
    #pragma unroll
    for (int m = 1; m < 32; m <<= 1){ vs += __shfl_xor(vs, m); vd += __shfl_xor(vd, m); }
    if (half == 0){
        h2a[(size_t)n * 32 + c] = s;
        if (c == 0){ al_s2[n] = vs; al_d2[n] = vd; }
    }
}

// ================= layer 2: FUSED softmax + aggregate (3-deep pipeline) =================
__global__ __launch_bounds__(256) void k_node2(const int* __restrict__ src32, const u16* __restrict__ ale2p,
                                               const int* __restrict__ offsets,
                                               const float* __restrict__ al_s, const float* __restrict__ al_d,
                                               const float* __restrict__ h2a, const float* __restrict__ b2,
                                               float* __restrict__ dout, float* __restrict__ rzv){
    int wave = threadIdx.x >> 6, lane = threadIdx.x & 63;
    int n = blockIdx.x * 4 + wave;
    int start = offsets[n], end = offsets[n + 1];
    int degr = end - start - 1;
    float aldn = al_d[n];
    int g = lane >> 3, l = lane & 7;                 // 8 edges in flight, channels l*4..l*4+3
    const f32x4* h2v = (const f32x4*)h2a;            // 8 f32x4 per row
    f32x4 acc = (f32x4){0.f, 0.f, 0.f, 0.f};
    float z = 0.f, sa = 0.f;
    int i = start + 1 + g;
    int i1 = i + 8, i2 = i + 16;
    int src0 = (i  < end) ? __builtin_nontemporal_load(src32 + i)  : n;
    int src1 = (i1 < end) ? __builtin_nontemporal_load(src32 + i1) : n;
    float a0   = (i < end) ? bf2f(__builtin_nontemporal_load(ale2p + i)) : 0.f;
    float als0 = al_s[src0];
    f32x4 v0 = h2v[(size_t)src0 * 8 + l];
    while (i < end){
        int src2 = (i2 < end) ? __builtin_nontemporal_load(src32 + i2) : n;
        float a1v   = (i1 < end) ? bf2f(__builtin_nontemporal_load(ale2p + i1)) : 0.f;
        float als1 = al_s[src1];
        f32x4 v1 = h2v[(size_t)src1 * 8 + l];
        float e = __expf(lreluf(als0 + aldn + a0));
        z += e; sa += a0;
        #pragma unroll
        for (int k = 0; k < 4; k++) acc[k] += e * v0[k];
        i = i1; i1 = i2; i2 += 8;
        src1 = src2; a0 = a1v; als0 = als1; v0 = v1;
    }
    z += __shfl_xor(z, 8); z += __shfl_xor(z, 16); z += __shfl_xor(z, 32);
    sa += __shfl_xor(sa, 8); sa += __shfl_xor(sa, 16); sa += __shfl_xor(sa, 32);
    float mal = sa / fmaxf((float)degr, 1.f);
    float ps = __expf(lreluf(al_s[n] + aldn + mal));
    z += ps;
    float rz = 1.f / z;
    if (g == 0){                                     // self contribution
        f32x4 v = h2v[(size_t)n * 8 + l];
        #pragma unroll
        for (int k = 0; k < 4; k++) acc[k] += ps * v[k];
    }
    if (lane == 0){
        rzv[n] = rz;
        dout[OUT_AL + NE + n] = ps * rz;             // self-loop alpha
        dout[OUT_EI + NE + n] = (float)n;            // self-loop edge_index entries
        dout[OUT_EI + NE2 + NE + n] = (float)n;
    }
    #pragma unroll
    for (int k = 0; k < 4; k++){
        acc[k] += __shfl_xor(acc[k], 8);
        acc[k] += __shfl_xor(acc[k], 16);
        acc[k] += __shfl_xor(acc[k], 32);
    }
    if (g == 0){
        f32x4 w;
        #pragma unroll
        for (int k = 0; k < 4; k++) w[k] = eluf(acc[k] + b2[l * 4 + k]);
        ((f32x4*)dout)[(size_t)n * 8 + l] = w;
    }
}

// alpha + edge_index for real edges, original edge order: all writes sequential
__global__ __launch_bounds__(256) void k_alpha(const int* __restrict__ ei, const u16* __restrict__ ale2,
                                               const float* __restrict__ al_s, const float* __restrict__ al_d,
                                               const float* __restrict__ rzv, float* __restrict__ dout){
    int e = blockIdx.x * 256 + threadIdx.x;          // NE exact
    int src = ei[e], dst = ei[NE + e];
    float a = bf2f(ale2[e]);
    float ev = __expf(lreluf(al_s[src] + al_d[dst] + a));
    __builtin_nontemporal_store(ev * rzv[dst], &dout[OUT_AL + e]);
    __builtin_nontemporal_store((float)src, &dout[OUT_EI + e]);
    __builtin_nontemporal_store((float)dst, &dout[OUT_EI + NE2 + e]);
}

extern "C" void kernel_launch(void* const* d_in, const int* in_sizes, int n_in,
                              void* d_out, int out_size, void* d_ws, size_t ws_size,
                              hipStream_t stream) {
    const float* x     = (const float*)d_in[0];
    const int*   ei    = (const int*)d_in[1];
    const float* eattr = (const float*)d_in[2];
    const float* W1    = (const float*)d_in[3];
    const float* W1e   = (const float*)d_in[4];
    const float* a1s   = (const float*)d_in[5];
    const float* a1d   = (const float*)d_in[6];
    const float* a1e   = (const float*)d_in[7];
    const float* b1    = (const float*)d_in[8];
    const float* W2    = (const float*)d_in[9];
    const float* W2e   = (const float*)d_in[10];
    const float* a2s   = (const float*)d_in[11];
    const float* a2d   = (const float*)d_in[12];
    const float* a2e   = (const float*)d_in[13];
    const float* b2    = (const float*)d_in[14];
    float* dout = (float*)d_out;

    char* ws = (char*)d_ws;
    size_t off = 0;
    auto alloc = [&](size_t bytes) -> void* {
        void* p = ws + off;
        off += (bytes + 255) & ~(size_t)255;
        return p;
    };
    // --- zero-initialized: bucket counters only ---
    int* bcnt = (int*)alloc((size_t)NB * 4);
    size_t zero_bytes = off;
    // --- rest fully written before read ---
    int*     offsets = (int*)alloc((size_t)(NN + 1) * 4);
    int*     bbase   = (int*)alloc((size_t)(NB + 1) * 4);
    int*     bcur    = (int*)alloc((size_t)NB * 4);
    u32*     binsP   = (u32*)alloc((size_t)NE * 4);          // dead after k_fscatter
    uint2*   binsA   = (uint2*)alloc((size_t)NE * 8);        // dead after k_fscatter
    u16*     binsA2  = (u16*)alloc((size_t)NE * 2);          // dead after k_fscatter
    int*     src32   = (int*)alloc((size_t)NE2 * 4);
    uint2*   ale1p   = (uint2*)alloc((size_t)NE2 * 8);
    u16*     ale2p   = (u16*)alloc((size_t)NE2 * 2);
    float*   q1      = (float*)alloc(64 * 4);
    float*   q2      = (float*)alloc(16 * 4);
    u16*     ale1    = (u16*)alloc((size_t)NE * 4 * 2);      // dead after k_bscatter
    u16*     ale2    = (u16*)alloc((size_t)NE * 2);          // live until k_alpha
    float*   al_s1   = (float*)alloc((size_t)NN * 4 * 4);
    float*   al_d1   = (float*)alloc((size_t)NN * 4 * 4);
    u16*     h1      = (u16*)alloc((size_t)NN * 128 * 2);    // live until k_node1 done
    // aliases into dead bin regions (safe: written by k_node1, after k_fscatter)
    float* h2a   = (float*)binsA;                            // NN*32*4 = 12.8 MB in 12.8 MB
    float* al_s2 = (float*)binsP;                            // 3*NNP*4 = 1.2 MB in 6.4 MB
    float* al_d2 = al_s2 + NNP;
    float* rzv   = al_d2 + NNP;

    const int TB = 256;
    hipMemsetAsync(d_ws, 0, zero_bytes, stream);

    // precomputes
    k_q<<<1, 64, 0, stream>>>(W1e, a1e, W2e, a2e, q1, q2);
    k_ale<<<NE * 4 / TB, TB, 0, stream>>>(eattr, q1, q2, ale1, ale2);
    // bucketed CSR build
    k_bhist<<<NBB, TB, 0, stream>>>(ei, bcnt);
    k_bscan<<<1, 512, 0, stream>>>(bcnt, bbase, bcur);
    k_bscatter<<<NBB, TB, 0, stream>>>(ei, ale1, ale2, bcur, binsP, binsA, binsA2);
    k_fscatter<<<NB, TB, 0, stream>>>(binsP, binsA, binsA2, bbase, offsets, src32, ale1p, ale2p);
    // layer 1 (al1 fused into gemm1; gemm2+al2 fused into node1)
    k_gemm1<<<(NN + 63) / 64, TB, 0, stream>>>(x, W1, a1s, a1d, h1, al_s1, al_d1);
    k_node1<<<NN / 4, TB, 0, stream>>>(src32, (const u16*)ale1p, offsets, al_s1, al_d1, h1, b1,
                                       W2, a2s, a2d, h2a, al_s2, al_d2);
    // layer 2
    k_node2<<<NN / 4, TB, 0, stream>>>(src32, ale2p, offsets, al_s2, al_d2, h2a, b2, dout, rzv);
    k_alpha<<<NE / TB, TB, 0, stream>>>(ei, ale2, al_s2, al_d2, rzv, dout);
}